// Round 1
// baseline (711.216 us; speedup 1.0000x reference)
//
#include <hip/hip_runtime.h>
#include <cstdint>
#include <cstddef>

typedef unsigned short u16;
typedef __attribute__((ext_vector_type(8))) short short8;   // 8 x bf16 (4 VGPRs) MFMA A/B frag
typedef __attribute__((ext_vector_type(4))) short short4v;
typedef __attribute__((ext_vector_type(4))) float f32x4;    // MFMA C/D frag

#define NTOK 65536
#define HID 512
#define NVOCAB 1024

// ---------- bf16 helpers (raw-bit, RNE) ----------
__device__ __forceinline__ u16 f2bf(float f) {
  union { float f; uint32_t u; } v; v.f = f;
  uint32_t r = (v.u + 0x7FFFu + ((v.u >> 16) & 1u)) >> 16;
  return (u16)r;
}
__device__ __forceinline__ float bf2f(u16 b) {
  union { uint32_t u; float f; } v; v.u = ((uint32_t)b) << 16;
  return v.f;
}

// async global->LDS, 16B per lane; LDS dest = wave-uniform base + lane*16
__device__ __forceinline__ void gl_lds16(const u16* g, u16* l) {
  __builtin_amdgcn_global_load_lds(
      (const __attribute__((address_space(1))) uint32_t*)g,
      (__attribute__((address_space(3))) uint32_t*)l, 16, 0, 0);
}

// ---------- hash constants (precomputed from reference) ----------
__constant__ uint32_t P24[24] = {
  2654435761u, 2246822519u, 3266489917u, 2028178513u, 1220703125u,
  1610612741u, 805306457u, 402653189u, 3674653429u, 2860486313u,
  1073676287u, 2971215073u, 1500450271u, 3267000013u, 2654435789u,
  4049292737u, 2246822531u, 3266489927u, 2028178519u, 1220703133u,
  1610612743u, 805306459u, 402653191u, 3674653433u};
__constant__ unsigned char OFFS[32][3] = {
  {1,0,0},{2,0,0},{3,0,0},{4,0,0},{5,0,0},{6,0,0},{7,0,0},{8,0,0},
  {1,2,0},{2,3,0},{3,4,0},{1,3,0},{2,4,0},{1,4,0},{1,5,0},{2,5,0},
  {3,5,0},{1,6,0},{2,6,0},{1,7,0},
  {1,2,3},{1,2,4},{1,3,5},{2,3,4},{1,2,5},{1,3,4},{2,4,6},{1,4,7},
  {1,8,0},{1,9,0},{1,10,0},{1,11,0}};
__constant__ unsigned char PLEN[32] = {
  1,1,1,1,1,1,1,1, 2,2,2,2,2,2,2,2,2,2,2,2, 3,3,3,3,3,3,3,3, 2,2,2,2};

// ---------- weight fp32 -> bf16 (4 elems/thread) ----------
__global__ __launch_bounds__(256) void cvt_bf16(const float* __restrict__ src,
                                                u16* __restrict__ dst, int n) {
  int i = (blockIdx.x * 256 + threadIdx.x) * 4;
  if (i < n) {
    float4 f = *(const float4*)(src + i);
    short4v o;
    o[0] = (short)f2bf(f.x); o[1] = (short)f2bf(f.y);
    o[2] = (short)f2bf(f.z); o[3] = (short)f2bf(f.w);
    *(short4v*)(dst + i) = o;
  }
}

// ---------- features: byte-embed + 32 hash embeds -> [NTOK,512] bf16 ----------
// block = 256 threads = 8 tokens x 32 lanes
__global__ __launch_bounds__(256) void feat_kernel(
    const int* __restrict__ chars, const float* __restrict__ byte_embed,
    const float* __restrict__ hash_tables, u16* __restrict__ feat)
{
  const int tid = threadIdx.x;
  const int tl  = tid >> 5;        // token-local 0..7
  const int sub = tid & 31;        // segment / table id
  const size_t t = (size_t)blockIdx.x * 8 + tl;
  const int s = (int)(t & 2047);   // position within sequence
  const int c = chars[t];

  // byte embedding: 8 consecutive floats -> bf16
  {
    const float* src = byte_embed + ((size_t)c << 8) + (sub << 3);
    float4 f0 = ((const float4*)src)[0];
    float4 f1 = ((const float4*)src)[1];
    short8 o;
    o[0]=(short)f2bf(f0.x); o[1]=(short)f2bf(f0.y); o[2]=(short)f2bf(f0.z); o[3]=(short)f2bf(f0.w);
    o[4]=(short)f2bf(f1.x); o[5]=(short)f2bf(f1.y); o[6]=(short)f2bf(f1.z); o[7]=(short)f2bf(f1.w);
    *(short8*)(feat + t * HID + (sub << 3)) = o;
  }

  // hash table `sub`
  {
    const int i = sub;
    const int pl = (int)PLEN[i];
    long long h = 0;
    #pragma unroll
    for (int k = 0; k < 3; ++k) {
      if (k < pl) {
        const int off = (int)OFFS[i][k];
        const long long tok = (s >= off) ? (long long)chars[t - off] : 0ll;
        h ^= tok * (long long)P24[(3 * i + k) % 24];   // tok<2^10, prime<2^32: no ovf
      }
    }
    const int idx_lo = (int)(h & 4095);                // h >= 0
    const long long sp = (long long)P24[(3 * i + pl) % 24];
    // int64 wrap-around multiply (matches jax int64 semantics), arithmetic >>16
    const long long prod = (long long)((unsigned long long)h * (unsigned long long)sp);
    const long long h2 = h ^ (prod >> 16);
    const int idx_hi = (int)(h2 & 4095);               // floored mod == & for pow2
    const float frac = ((float)(int)((h >> 3) & 255) / 255.0f) * 0.4f;
    const float om = 1.0f - frac;

    const float* plo = hash_tables + (((size_t)i << 12) + (size_t)idx_lo) * 8;
    const float* phi = hash_tables + (((size_t)i << 12) + (size_t)idx_hi) * 8;
    float4 a0 = ((const float4*)plo)[0], a1 = ((const float4*)plo)[1];
    float4 b0 = ((const float4*)phi)[0], b1 = ((const float4*)phi)[1];
    short8 o;
    o[0]=(short)f2bf(a0.x*om + b0.x*frac); o[1]=(short)f2bf(a0.y*om + b0.y*frac);
    o[2]=(short)f2bf(a0.z*om + b0.z*frac); o[3]=(short)f2bf(a0.w*om + b0.w*frac);
    o[4]=(short)f2bf(a1.x*om + b1.x*frac); o[5]=(short)f2bf(a1.y*om + b1.y*frac);
    o[6]=(short)f2bf(a1.z*om + b1.z*frac); o[7]=(short)f2bf(a1.w*om + b1.w*frac);
    *(short8*)(feat + t * HID + 256 + (i << 3)) = o;
  }
}

// ---------- bf16 GEMM: C[M,N] = act(A[M,K] @ Bt[N,K]^T + bias) (+resid) ----------
// m97 recipe: 128x128 tile, BK=32, 4 waves each 64x64 via 16x16x32 MFMA,
// global_load_lds width-16 staging.
template<bool RELU, bool RESID, bool F32OUT>
__global__ __launch_bounds__(256)
void gemm_bt(const u16* __restrict__ A, const u16* __restrict__ Bt,
             const float* __restrict__ bias, const u16* __restrict__ resid,
             void* __restrict__ outp, int M, int N, int K)
{
  __shared__ __align__(16) u16 lA[128 * 32];
  __shared__ __align__(16) u16 lB[128 * 32];
  const int tid  = threadIdx.x;
  const int wave = tid >> 6;
  const int lane = tid & 63;
  const int m0 = blockIdx.y << 7;
  const int n0 = blockIdx.x << 7;
  const int wr = wave >> 1, wc = wave & 1;   // 2x2 wave grid, 64x64 each

  f32x4 acc[4][4];
  #pragma unroll
  for (int i = 0; i < 4; ++i)
    #pragma unroll
    for (int j = 0; j < 4; ++j) acc[i][j] = (f32x4){0.f, 0.f, 0.f, 0.f};

  // staging: wave handles chunks c0,c0+1 (16 rows each); lane l -> row l>>2, col (l&3)*8
  const int c0 = wave << 1;
  const int rr = lane >> 2;
  const int cc = (lane & 3) << 3;
  const u16* gA0 = A  + (size_t)(m0 + (c0 << 4) + rr) * K + cc;
  const u16* gB0 = Bt + (size_t)(n0 + (c0 << 4) + rr) * K + cc;
  const int mrow = lane & 15;
  const int kg   = (lane >> 4) << 3;

  for (int k0 = 0; k0 < K; k0 += 32) {
    gl_lds16(gA0 + k0,                   &lA[(size_t)c0 << 9]);
    gl_lds16(gA0 + (size_t)16 * K + k0,  &lA[(size_t)(c0 + 1) << 9]);
    gl_lds16(gB0 + k0,                   &lB[(size_t)c0 << 9]);
    gl_lds16(gB0 + (size_t)16 * K + k0,  &lB[(size_t)(c0 + 1) << 9]);
    __syncthreads();

    short8 a[4], b[4];
    #pragma unroll
    for (int tI = 0; tI < 4; ++tI) {
      a[tI] = *(const short8*)&lA[((wr << 6) + (tI << 4) + mrow) * 32 + kg];
      b[tI] = *(const short8*)&lB[((wc << 6) + (tI << 4) + mrow) * 32 + kg];
    }
    #pragma unroll
    for (int mt = 0; mt < 4; ++mt)
      #pragma unroll
      for (int nt = 0; nt < 4; ++nt)
        acc[mt][nt] = __builtin_amdgcn_mfma_f32_16x16x32_bf16(a[mt], b[nt], acc[mt][nt], 0, 0, 0);
    __syncthreads();
  }

  // epilogue: C/D layout col=lane&15 (n), row=(lane>>4)*4+r (m)
  const int lm = (lane >> 4) << 2;
  const int ln = lane & 15;
  #pragma unroll
  for (int nt = 0; nt < 4; ++nt) {
    const int col = n0 + (wc << 6) + (nt << 4) + ln;
    const float bs = bias[col];
    #pragma unroll
    for (int mt = 0; mt < 4; ++mt) {
      #pragma unroll
      for (int r = 0; r < 4; ++r) {
        const int row = m0 + (wr << 6) + (mt << 4) + lm + r;
        float v = acc[mt][nt][r] + bs;
        if (RELU) v = fmaxf(v, 0.0f);
        if (RESID) v += bf2f(resid[(size_t)row * N + col]);
        if (F32OUT) ((float*)outp)[(size_t)row * N + col] = v;
        else        ((u16*)  outp)[(size_t)row * N + col] = f2bf(v);
      }
    }
  }
}

extern "C" void kernel_launch(void* const* d_in, const int* in_sizes, int n_in,
                              void* d_out, int out_size, void* d_ws, size_t ws_size,
                              hipStream_t stream) {
  const int*   chars      = (const int*)  d_in[0];
  const float* byte_embed = (const float*)d_in[1];
  const float* hash_tabs  = (const float*)d_in[2];
  const float* w_in       = (const float*)d_in[3];
  const float* b_in       = (const float*)d_in[4];
  const float* mlp_ws     = (const float*)d_in[5];
  const float* mlp_bs     = (const float*)d_in[6];
  const float* w_out      = (const float*)d_in[7];
  const float* b_out      = (const float*)d_in[8];

  // ws layout (u16 elems): weights bf16 then two 65536x512 activation buffers
  u16* wInB  = (u16*)d_ws;                 // 262144
  u16* wMlpB = wInB  + 262144;             // 786432 (3 x 512x512)
  u16* wOutB = wMlpB + 786432;             // 524288
  u16* buf0  = wOutB + 524288;             // NTOK*HID
  u16* buf1  = buf0  + (size_t)NTOK * HID; // NTOK*HID
  // total = 137,363,456 bytes

  dim3 blk(256);
  cvt_bf16<<<dim3(262144 / 1024), blk, 0, stream>>>(w_in,   wInB,  262144);
  cvt_bf16<<<dim3(786432 / 1024), blk, 0, stream>>>(mlp_ws, wMlpB, 786432);
  cvt_bf16<<<dim3(524288 / 1024), blk, 0, stream>>>(w_out,  wOutB, 524288);

  feat_kernel<<<dim3(NTOK / 8), blk, 0, stream>>>(chars, byte_embed, hash_tabs, buf0);

  // h0 = relu(features @ w_in^T + b_in)
  gemm_bt<true,  false, false><<<dim3(4, 512), blk, 0, stream>>>(
      buf0, wInB, b_in, (const u16*)nullptr, (void*)buf1, NTOK, HID, HID);
  // residual blocks: h = relu(h @ W^T + b) + h
  gemm_bt<true,  true,  false><<<dim3(4, 512), blk, 0, stream>>>(
      buf1, wMlpB,          mlp_bs,        buf1, (void*)buf0, NTOK, HID, HID);
  gemm_bt<true,  true,  false><<<dim3(4, 512), blk, 0, stream>>>(
      buf0, wMlpB + 262144, mlp_bs + 512,  buf0, (void*)buf1, NTOK, HID, HID);
  gemm_bt<true,  true,  false><<<dim3(4, 512), blk, 0, stream>>>(
      buf1, wMlpB + 524288, mlp_bs + 1024, buf1, (void*)buf0, NTOK, HID, HID);
  // logits = h @ w_out^T + b_out  (fp32 out)
  gemm_bt<false, false, true><<<dim3(8, 512), blk, 0, stream>>>(
      buf0, wOutB, b_out, (const u16*)nullptr, d_out, NTOK, NVOCAB, HID);
}